// Round 7
// baseline (1584.708 us; speedup 1.0000x reference)
//
#include <hip/hip_runtime.h>
#include <hip/hip_bf16.h>
#include <math.h>

#define NN 100000
#define NE 1600000
#define NFE 128
#define SCAN_NB 98   // ceil(NN/1024)

using f32x4 = __attribute__((ext_vector_type(4))) float;
using s16x8 = __attribute__((ext_vector_type(8))) short;

__device__ __forceinline__ short bf16_rne(float x) {
  unsigned u = __float_as_uint(x);
  unsigned r = u + 0x7FFFu + ((u >> 16) & 1u);
  return (short)(r >> 16);
}
__device__ __forceinline__ float bf16_f(short s) {
  return __uint_as_float(((unsigned)(unsigned short)s) << 16);
}
__device__ __forceinline__ float leaky(float v) {
  return v >= 0.0f ? v : 0.02f * v;
}
__device__ __forceinline__ float4 fmax4(float4 a, float4 b) {
  return make_float4(fmaxf(a.x, b.x), fmaxf(a.y, b.y), fmaxf(a.z, b.z), fmaxf(a.w, b.w));
}

// ---------------- CSR build (once per call) ----------------

__global__ __launch_bounds__(256) void k_zero_i32(int* __restrict__ p, int n) {
  int i = blockIdx.x * blockDim.x + threadIdx.x;
  if (i < n) p[i] = 0;
}

__global__ __launch_bounds__(256) void k_hist(const int* __restrict__ dst,
                                              int* __restrict__ counts) {
  int e = blockIdx.x * blockDim.x + threadIdx.x;
  if (e < NE) atomicAdd(&counts[dst[e]], 1);
}

__global__ __launch_bounds__(256) void k_scan_sum(const int* __restrict__ counts,
                                                  int* __restrict__ bsum) {
  const int t = threadIdx.x;
  const int base = blockIdx.x * 1024 + t * 4;
  int4 c = make_int4(0, 0, 0, 0);
  if (base + 3 < NN) c = *(const int4*)(counts + base);
  else {
    if (base + 0 < NN) c.x = counts[base + 0];
    if (base + 1 < NN) c.y = counts[base + 1];
    if (base + 2 < NN) c.z = counts[base + 2];
  }
  int s = c.x + c.y + c.z + c.w;
#pragma unroll
  for (int off = 32; off; off >>= 1) s += __shfl_down(s, off, 64);
  __shared__ int ws[4];
  if ((t & 63) == 0) ws[t >> 6] = s;
  __syncthreads();
  if (t == 0) bsum[blockIdx.x] = ws[0] + ws[1] + ws[2] + ws[3];
}

__global__ __launch_bounds__(128) void k_scan_top(const int* __restrict__ bsum,
                                                  int* __restrict__ boff) {
  __shared__ int v[128];
  const int t = threadIdx.x;
  int mine = (t < SCAN_NB) ? bsum[t] : 0;
  v[t] = mine;
  __syncthreads();
  for (int off = 1; off < 128; off <<= 1) {
    int u = (t >= off) ? v[t - off] : 0;
    __syncthreads();
    v[t] += u;
    __syncthreads();
  }
  if (t < SCAN_NB) boff[t] = v[t] - mine;  // exclusive
}

__global__ __launch_bounds__(256) void k_scan_blk(const int* __restrict__ counts,
                                                  const int* __restrict__ boff,
                                                  int* __restrict__ row_ptr,
                                                  int* __restrict__ cursor) {
  __shared__ int part[256];
  const int t = threadIdx.x;
  const int base = blockIdx.x * 1024 + t * 4;
  int4 c = make_int4(0, 0, 0, 0);
  if (base + 3 < NN) c = *(const int4*)(counts + base);
  else {
    if (base + 0 < NN) c.x = counts[base + 0];
    if (base + 1 < NN) c.y = counts[base + 1];
    if (base + 2 < NN) c.z = counts[base + 2];
  }
  const int s = c.x + c.y + c.z + c.w;
  part[t] = s;
  __syncthreads();
  for (int off = 1; off < 256; off <<= 1) {
    int u = (t >= off) ? part[t - off] : 0;
    __syncthreads();
    part[t] += u;
    __syncthreads();
  }
  int excl = boff[blockIdx.x] + part[t] - s;
  int4 r;
  r.x = excl;
  r.y = r.x + c.x;
  r.z = r.y + c.y;
  r.w = r.z + c.z;
  const int4 z = make_int4(0, 0, 0, 0);
  if (base + 3 < NN) {
    *(int4*)(row_ptr + base) = r;
    *(int4*)(cursor + base) = z;
  } else {
    if (base + 0 < NN) { row_ptr[base + 0] = r.x; cursor[base + 0] = 0; }
    if (base + 1 < NN) { row_ptr[base + 1] = r.y; cursor[base + 1] = 0; }
    if (base + 2 < NN) { row_ptr[base + 2] = r.z; cursor[base + 2] = 0; }
  }
  if (blockIdx.x == 0 && t == 0) row_ptr[NN] = NE;
}

__global__ __launch_bounds__(256) void k_fill(const int* __restrict__ src,
                                              const int* __restrict__ dst,
                                              const int* __restrict__ row_ptr,
                                              int* __restrict__ cursor,
                                              int* __restrict__ nbr) {
  int e = blockIdx.x * blockDim.x + threadIdx.x;
  if (e >= NE) return;
  int d = dst[e];
  int p = atomicAdd(&cursor[d], 1);
  nbr[row_ptr[d] + p] = src[e];  // order within row nondeterministic; max is invariant
}

// ---------------- weight prep: f32 -> bf16 hi/lo ----------------

__global__ __launch_bounds__(256) void k_prep_w(const float* __restrict__ Wl,
                                                const float* __restrict__ Wr,
                                                short* __restrict__ wb) {
  int idx = blockIdx.x * 256 + threadIdx.x;
  if (idx >= 7 * 2 * 16384) return;
  int li = idx / 32768;
  int rem = idx % 32768;
  int seg = rem / 16384;
  int ok = rem % 16384;
  float v = seg ? Wr[li * 16384 + ok] : Wl[li * 16384 + ok];
  short hi = bf16_rne(v);
  short lo = bf16_rne(v - bf16_f(hi));
  short* base = wb + (size_t)li * 65536 + seg * 32768;
  base[ok] = hi;
  base[16384 + ok] = lo;
}

// ---------------- fused hidden layer: gather-max + split-bf16 MFMA, 32-node tile ----------------
// hout = leaky( (max_{s in N(n)} hin[s]) @ Wl^T + bl + hin @ Wr^T )
// LDS holds ONLY the aggregated tile (hi/lo bf16, XOR-swizzled). Root-branch
// A-fragments are loaded straight from hin (L1/L2-resident 16KB tile).

__global__ __launch_bounds__(256, 8) void k_layer_fused(const float* __restrict__ hin,
                                                        const int* __restrict__ row_ptr,
                                                        const int* __restrict__ nbr,
                                                        const short* __restrict__ wbl,
                                                        const float* __restrict__ bl,
                                                        float* __restrict__ hout) {
  __shared__ __align__(16) char smem[2 * 8192];  // agg hi | agg lo
  const int t = threadIdx.x;
  const int base = blockIdx.x * 32;

  // --- gather-max into the A tile: 8 lanes x 64B per row, 32 rows in parallel ---
  {
    char* ahi = smem;
    char* alo = smem + 8192;
    const int r = t >> 3;          // row 0..31
    const int lg = t & 7;
    const int c0 = lg * 16;        // 16 channels = 64B per lane
    const int n = base + r;
    const int start = row_ptr[n], end = row_ptr[n + 1];
    const float NI = __int_as_float(0xFF800000);
    float4 a0 = make_float4(NI, NI, NI, NI), a1 = a0, a2 = a0, a3 = a0;
    int j = start;
    for (; j + 2 <= end; j += 2) {
      int s0 = nbr[j], s1 = nbr[j + 1];
      const float4* p0 = (const float4*)(hin + (size_t)s0 * NFE + c0);
      const float4* p1 = (const float4*)(hin + (size_t)s1 * NFE + c0);
      float4 u0 = p0[0], u1 = p0[1], u2 = p0[2], u3 = p0[3];
      float4 w0 = p1[0], w1 = p1[1], w2 = p1[2], w3 = p1[3];
      a0 = fmax4(a0, fmax4(u0, w0));
      a1 = fmax4(a1, fmax4(u1, w1));
      a2 = fmax4(a2, fmax4(u2, w2));
      a3 = fmax4(a3, fmax4(u3, w3));
    }
    if (j < end) {
      const float4* p0 = (const float4*)(hin + (size_t)nbr[j] * NFE + c0);
      a0 = fmax4(a0, p0[0]);
      a1 = fmax4(a1, p0[1]);
      a2 = fmax4(a2, p0[2]);
      a3 = fmax4(a3, p0[3]);
    }
    if (start == end) {
      a0 = make_float4(0.f, 0.f, 0.f, 0.f);
      a1 = a0; a2 = a0; a3 = a0;
    }
    float f[16] = {a0.x, a0.y, a0.z, a0.w, a1.x, a1.y, a1.z, a1.w,
                   a2.x, a2.y, a2.z, a2.w, a3.x, a3.y, a3.z, a3.w};
    s16x8 hv0, hv1, lv0, lv1;
#pragma unroll
    for (int q = 0; q < 8; ++q) {
      short h0 = bf16_rne(f[q]);
      hv0[q] = h0;
      lv0[q] = bf16_rne(f[q] - bf16_f(h0));
      short h1 = bf16_rne(f[q + 8]);
      hv1[q] = h1;
      lv1[q] = bf16_rne(f[q + 8] - bf16_f(h1));
    }
    const int ob = r * 256 + c0 * 2;
    const int sw = (r & 7) << 4;
    *(s16x8*)(ahi + (ob ^ sw))        = hv0;
    *(s16x8*)(ahi + ((ob + 16) ^ sw)) = hv1;
    *(s16x8*)(alo + (ob ^ sw))        = lv0;
    *(s16x8*)(alo + ((ob + 16) ^ sw)) = lv1;
  }
  __syncthreads();

  // --- split-bf16 MFMA: Ahi*Whi + Ahi*Wlo + Alo*Whi per branch ---
  const int w = t >> 6;        // wave id: cols 32w..32w+31
  const int l = t & 63;
  const int lr = l & 15;
  const int lk = (l >> 4) * 8;

  f32x4 acc[2][2] = {};        // [row tile][col tile]

#pragma unroll
  for (int seg = 0; seg < 2; ++seg) {
    const short* bhb = wbl + seg * 32768;
    const short* blb = wbl + seg * 32768 + 16384;
#pragma unroll
    for (int ks = 0; ks < 4; ++ks) {
      const int k0 = ks * 32;
      s16x8 ah0, ah1, al0, al1;
      if (seg == 0) {
        const char* ahi = smem;
        const char* alo = smem + 8192;
        int offa0 = (lr) * 256 + (k0 + lk) * 2;      offa0 ^= ((lr) & 7) << 4;
        int offa1 = (16 + lr) * 256 + (k0 + lk) * 2; offa1 ^= ((16 + lr) & 7) << 4;
        ah0 = *(const s16x8*)(smem + offa0);
        ah1 = *(const s16x8*)(smem + offa1);
        al0 = *(const s16x8*)(alo + offa0);
        al1 = *(const s16x8*)(alo + offa1);
        (void)ahi;
      } else {
        // root branch: A-frags straight from global (tile is L1/L2-hot)
#pragma unroll
        for (int rt = 0; rt < 2; ++rt) {
          const float* gp = hin + (size_t)(base + rt * 16 + lr) * NFE + k0 + lk;
          float4 g0 = *(const float4*)(gp);
          float4 g1 = *(const float4*)(gp + 4);
          float f[8] = {g0.x, g0.y, g0.z, g0.w, g1.x, g1.y, g1.z, g1.w};
          s16x8 hv, lv;
#pragma unroll
          for (int q = 0; q < 8; ++q) {
            short h = bf16_rne(f[q]);
            hv[q] = h;
            lv[q] = bf16_rne(f[q] - bf16_f(h));
          }
          if (rt == 0) { ah0 = hv; al0 = lv; }
          else         { ah1 = hv; al1 = lv; }
        }
      }
#pragma unroll
      for (int ct = 0; ct < 2; ++ct) {
        const int col = w * 32 + ct * 16 + lr;
        const s16x8 bh = *(const s16x8*)(bhb + col * 128 + k0 + lk);
        const s16x8 bl_ = *(const s16x8*)(blb + col * 128 + k0 + lk);
        acc[0][ct] = __builtin_amdgcn_mfma_f32_16x16x32_bf16(ah0, bh, acc[0][ct], 0, 0, 0);
        acc[1][ct] = __builtin_amdgcn_mfma_f32_16x16x32_bf16(ah1, bh, acc[1][ct], 0, 0, 0);
        acc[0][ct] = __builtin_amdgcn_mfma_f32_16x16x32_bf16(ah0, bl_, acc[0][ct], 0, 0, 0);
        acc[1][ct] = __builtin_amdgcn_mfma_f32_16x16x32_bf16(ah1, bl_, acc[1][ct], 0, 0, 0);
        acc[0][ct] = __builtin_amdgcn_mfma_f32_16x16x32_bf16(al0, bh, acc[0][ct], 0, 0, 0);
        acc[1][ct] = __builtin_amdgcn_mfma_f32_16x16x32_bf16(al1, bh, acc[1][ct], 0, 0, 0);
      }
    }
  }

  // epilogue: bias + leaky; C layout: col = lane&15, row = (lane>>4)*4 + reg
  const float bias0 = bl[w * 32 + lr];
  const float bias1 = bl[w * 32 + 16 + lr];
#pragma unroll
  for (int rt = 0; rt < 2; ++rt) {
#pragma unroll
    for (int r = 0; r < 4; ++r) {
      int node = base + 16 * rt + (l >> 4) * 4 + r;
      float* o = hout + (size_t)node * NFE + w * 32;
      o[lr]      = leaky(acc[rt][0][r] + bias0);
      o[16 + lr] = leaky(acc[rt][1][r] + bias1);
    }
  }
}

// ---------------- fused output layer: gather-max + tiny GEMV + tanh ----------------

__global__ __launch_bounds__(256) void k_final_fused(const float* __restrict__ h,
                                                     const int* __restrict__ row_ptr,
                                                     const int* __restrict__ nbr,
                                                     const float* __restrict__ Wlo,
                                                     const float* __restrict__ blo,
                                                     const float* __restrict__ Wro,
                                                     float* __restrict__ out) {
  const int wave = threadIdx.x >> 6;
  const int lane = threadIdx.x & 63;
  const int n = blockIdx.x * 4 + wave;
  if (n >= NN) return;
  const int c2 = lane * 2;
  const int start = row_ptr[n], end = row_ptr[n + 1];
  const float NI = __int_as_float(0xFF800000);
  float ax = NI, ay = NI;
  int j = start;
  for (; j + 4 <= end; j += 4) {
    int s0 = nbr[j], s1 = nbr[j + 1], s2 = nbr[j + 2], s3 = nbr[j + 3];
    float2 v0 = *(const float2*)(h + (size_t)s0 * NFE + c2);
    float2 v1 = *(const float2*)(h + (size_t)s1 * NFE + c2);
    float2 v2 = *(const float2*)(h + (size_t)s2 * NFE + c2);
    float2 v3 = *(const float2*)(h + (size_t)s3 * NFE + c2);
    ax = fmaxf(ax, fmaxf(fmaxf(v0.x, v1.x), fmaxf(v2.x, v3.x)));
    ay = fmaxf(ay, fmaxf(fmaxf(v0.y, v1.y), fmaxf(v2.y, v3.y)));
  }
  for (; j < end; ++j) {
    float2 v = *(const float2*)(h + (size_t)nbr[j] * NFE + c2);
    ax = fmaxf(ax, v.x);
    ay = fmaxf(ay, v.y);
  }
  if (start == end) { ax = 0.f; ay = 0.f; }
  const float2 hv = *(const float2*)(h + (size_t)n * NFE + c2);
  float p[3];
#pragma unroll
  for (int o = 0; o < 3; ++o) {
    const float2 wl = *(const float2*)(Wlo + o * NFE + c2);
    const float2 wr = *(const float2*)(Wro + o * NFE + c2);
    p[o] = ax * wl.x + ay * wl.y + hv.x * wr.x + hv.y * wr.y;
#pragma unroll
    for (int off = 32; off; off >>= 1) p[o] += __shfl_down(p[o], off, 64);
  }
  if (lane == 0) {
#pragma unroll
    for (int o = 0; o < 3; ++o)
      out[(size_t)n * 3 + o] = tanhf(p[o] + blo[o]) * 0.5f;
  }
}

// ---------------- launch ----------------

extern "C" void kernel_launch(void* const* d_in, const int* in_sizes, int n_in,
                              void* d_out, int out_size, void* d_ws, size_t ws_size,
                              hipStream_t stream) {
  const float* x   = (const float*)d_in[0];
  const int*   ei  = (const int*)d_in[1];
  const float* Wl  = (const float*)d_in[2];
  const float* bl  = (const float*)d_in[3];
  const float* Wr  = (const float*)d_in[4];
  const float* Wlo = (const float*)d_in[5];
  const float* blo = (const float*)d_in[6];
  const float* Wro = (const float*)d_in[7];
  float* out = (float*)d_out;

  const int* src = ei;
  const int* dst = ei + NE;

  char* ws = (char*)d_ws;
  size_t off = 0;
  auto alloc = [&](size_t bytes) { void* p = ws + off; off = (off + bytes + 255) & ~(size_t)255; return p; };
  int* counts  = (int*)alloc(sizeof(int) * NN);
  int* cursor  = (int*)alloc(sizeof(int) * NN);
  int* row_ptr = (int*)alloc(sizeof(int) * (NN + 1));
  int* nbr     = (int*)alloc(sizeof(int) * NE);
  int* bsum    = (int*)alloc(sizeof(int) * 128);
  int* boff    = (int*)alloc(sizeof(int) * 128);
  short* wb    = (short*)alloc(sizeof(short) * 7 * 65536);
  const size_t hbytes = (size_t)NN * NFE * sizeof(float);
  float* hA  = (float*)alloc(hbytes);
  float* hB  = (float*)alloc(hbytes);

  const int EB = (NE + 255) / 256;

  k_prep_w<<<(7 * 32768 + 255) / 256, 256, 0, stream>>>(Wl, Wr, wb);
  k_zero_i32<<<(NN + 255) / 256, 256, 0, stream>>>(counts, NN);
  k_hist<<<EB, 256, 0, stream>>>(dst, counts);
  k_scan_sum<<<SCAN_NB, 256, 0, stream>>>(counts, bsum);
  k_scan_top<<<1, 128, 0, stream>>>(bsum, boff);
  k_scan_blk<<<SCAN_NB, 256, 0, stream>>>(counts, boff, row_ptr, cursor);
  k_fill<<<EB, 256, 0, stream>>>(src, dst, row_ptr, cursor, nbr);

  const float* hin = x;
  float* bufs[2] = {hA, hB};
  for (int i = 0; i < 7; ++i) {
    float* hout = bufs[i & 1];
    k_layer_fused<<<NN / 32, 256, 0, stream>>>(hin, row_ptr, nbr,
                                               wb + (size_t)i * 65536,
                                               bl + (size_t)i * NFE, hout);
    hin = hout;
  }

  k_final_fused<<<(NN + 3) / 4, 256, 0, stream>>>(hin, row_ptr, nbr, Wlo, blo, Wro, out);
}

// Round 8
// 1514.791 us; speedup vs baseline: 1.0462x; 1.0462x over previous
//
#include <hip/hip_runtime.h>
#include <hip/hip_bf16.h>
#include <math.h>

#define NN 100000
#define NE 1600000
#define NFE 128
#define SCAN_NB 98    // ceil(NN/1024)
#define NT_TOTAL 3125 // NN/32
#define PIPE_GRID 512

using f32x4 = __attribute__((ext_vector_type(4))) float;
using s16x8 = __attribute__((ext_vector_type(8))) short;
using s16x4 = __attribute__((ext_vector_type(4))) short;

__device__ __forceinline__ short bf16_rne(float x) {
  unsigned u = __float_as_uint(x);
  unsigned r = u + 0x7FFFu + ((u >> 16) & 1u);
  return (short)(r >> 16);
}
__device__ __forceinline__ float bf16_f(short s) {
  return __uint_as_float(((unsigned)(unsigned short)s) << 16);
}
__device__ __forceinline__ float leaky(float v) {
  return v >= 0.0f ? v : 0.02f * v;
}
__device__ __forceinline__ float4 fmax4(float4 a, float4 b) {
  return make_float4(fmaxf(a.x, b.x), fmaxf(a.y, b.y), fmaxf(a.z, b.z), fmaxf(a.w, b.w));
}

// ---------------- CSR build (once per call) ----------------

__global__ __launch_bounds__(256) void k_zero_i32(int* __restrict__ p, int n) {
  int i = blockIdx.x * blockDim.x + threadIdx.x;
  if (i < n) p[i] = 0;
}

__global__ __launch_bounds__(256) void k_hist(const int* __restrict__ dst,
                                              int* __restrict__ counts) {
  int e = blockIdx.x * blockDim.x + threadIdx.x;
  if (e < NE) atomicAdd(&counts[dst[e]], 1);
}

__global__ __launch_bounds__(256) void k_scan_sum(const int* __restrict__ counts,
                                                  int* __restrict__ bsum) {
  const int t = threadIdx.x;
  const int base = blockIdx.x * 1024 + t * 4;
  int4 c = make_int4(0, 0, 0, 0);
  if (base + 3 < NN) c = *(const int4*)(counts + base);
  else {
    if (base + 0 < NN) c.x = counts[base + 0];
    if (base + 1 < NN) c.y = counts[base + 1];
    if (base + 2 < NN) c.z = counts[base + 2];
  }
  int s = c.x + c.y + c.z + c.w;
#pragma unroll
  for (int off = 32; off; off >>= 1) s += __shfl_down(s, off, 64);
  __shared__ int ws[4];
  if ((t & 63) == 0) ws[t >> 6] = s;
  __syncthreads();
  if (t == 0) bsum[blockIdx.x] = ws[0] + ws[1] + ws[2] + ws[3];
}

__global__ __launch_bounds__(128) void k_scan_top(const int* __restrict__ bsum,
                                                  int* __restrict__ boff) {
  __shared__ int v[128];
  const int t = threadIdx.x;
  int mine = (t < SCAN_NB) ? bsum[t] : 0;
  v[t] = mine;
  __syncthreads();
  for (int off = 1; off < 128; off <<= 1) {
    int u = (t >= off) ? v[t - off] : 0;
    __syncthreads();
    v[t] += u;
    __syncthreads();
  }
  if (t < SCAN_NB) boff[t] = v[t] - mine;  // exclusive
}

__global__ __launch_bounds__(256) void k_scan_blk(const int* __restrict__ counts,
                                                  const int* __restrict__ boff,
                                                  int* __restrict__ row_ptr,
                                                  int* __restrict__ cursor) {
  __shared__ int part[256];
  const int t = threadIdx.x;
  const int base = blockIdx.x * 1024 + t * 4;
  int4 c = make_int4(0, 0, 0, 0);
  if (base + 3 < NN) c = *(const int4*)(counts + base);
  else {
    if (base + 0 < NN) c.x = counts[base + 0];
    if (base + 1 < NN) c.y = counts[base + 1];
    if (base + 2 < NN) c.z = counts[base + 2];
  }
  const int s = c.x + c.y + c.z + c.w;
  part[t] = s;
  __syncthreads();
  for (int off = 1; off < 256; off <<= 1) {
    int u = (t >= off) ? part[t - off] : 0;
    __syncthreads();
    part[t] += u;
    __syncthreads();
  }
  int excl = boff[blockIdx.x] + part[t] - s;
  int4 r;
  r.x = excl;
  r.y = r.x + c.x;
  r.z = r.y + c.y;
  r.w = r.z + c.z;
  const int4 z = make_int4(0, 0, 0, 0);
  if (base + 3 < NN) {
    *(int4*)(row_ptr + base) = r;
    *(int4*)(cursor + base) = z;
  } else {
    if (base + 0 < NN) { row_ptr[base + 0] = r.x; cursor[base + 0] = 0; }
    if (base + 1 < NN) { row_ptr[base + 1] = r.y; cursor[base + 1] = 0; }
    if (base + 2 < NN) { row_ptr[base + 2] = r.z; cursor[base + 2] = 0; }
  }
  if (blockIdx.x == 0 && t == 0) row_ptr[NN] = NE;
}

__global__ __launch_bounds__(256) void k_fill(const int* __restrict__ src,
                                              const int* __restrict__ dst,
                                              const int* __restrict__ row_ptr,
                                              int* __restrict__ cursor,
                                              int* __restrict__ nbr) {
  int e = blockIdx.x * blockDim.x + threadIdx.x;
  if (e >= NE) return;
  int d = dst[e];
  int p = atomicAdd(&cursor[d], 1);
  nbr[row_ptr[d] + p] = src[e];  // order within row nondeterministic; max is invariant
}

// ---------------- weight prep: f32 -> bf16 hi/lo ----------------

__global__ __launch_bounds__(256) void k_prep_w(const float* __restrict__ Wl,
                                                const float* __restrict__ Wr,
                                                short* __restrict__ wb) {
  int idx = blockIdx.x * 256 + threadIdx.x;
  if (idx >= 7 * 2 * 16384) return;
  int li = idx / 32768;
  int rem = idx % 32768;
  int seg = rem / 16384;
  int ok = rem % 16384;
  float v = seg ? Wr[li * 16384 + ok] : Wl[li * 16384 + ok];
  short hi = bf16_rne(v);
  short lo = bf16_rne(v - bf16_f(hi));
  short* base = wb + (size_t)li * 65536 + seg * 32768;
  base[ok] = hi;
  base[16384 + ok] = lo;
}

// ---------------- producer/consumer fused layer ----------------
// 512 threads: waves 0-3 produce (gather-max + hi/lo convert + hin staging)
// into a double-buffered LDS tile; waves 4-7 consume (split-bf16 MFMA + store).
// Buffer layout (32KB each): [aggHi 8K][aggLo 8K][hinHi 8K][hinLo 8K],
// XOR swizzle on byte offsets: off ^= (row&7)<<4.

__global__ __launch_bounds__(512, 4) void k_layer_pipe(const float* __restrict__ hin,
                                                       const int* __restrict__ row_ptr,
                                                       const int* __restrict__ nbr,
                                                       const short* __restrict__ wbl,
                                                       const float* __restrict__ bl,
                                                       float* __restrict__ hout) {
  __shared__ __align__(16) char smem[2 * 32768];
  const int t = threadIdx.x;
  const int wave = t >> 6;
  const int bid = blockIdx.x;
  const int nt = (NT_TOTAL - bid + PIPE_GRID - 1) / PIPE_GRID;  // tiles for this block

  if (wave < 4) {
    // ---------------- producer ----------------
    const int pt = t;                 // 0..255
    const int srow = pt >> 3;         // staging row 0..31
    const int sc0 = (pt & 7) * 16;    // 16 channels
    const int grp = pt >> 5;          // gather group 0..7
    const int lg = pt & 31;
    const int c4 = lg << 2;           // 4 channels
    const float NI = __int_as_float(0xFF800000);

    for (int s = 0; s < nt; ++s) {
      const int base = (bid + s * PIPE_GRID) * 32;
      char* buf = smem + (s & 1) * 32768;
      char* aggHi = buf;
      char* aggLo = buf + 8192;
      char* hinHi = buf + 16384;
      char* hinLo = buf + 24576;

      // stage hin tile: 16 floats/thread
      {
        const float4* g = (const float4*)(hin + (size_t)(base + srow) * NFE + sc0);
        float4 v0 = g[0], v1 = g[1], v2 = g[2], v3 = g[3];
        float f[16] = {v0.x, v0.y, v0.z, v0.w, v1.x, v1.y, v1.z, v1.w,
                       v2.x, v2.y, v2.z, v2.w, v3.x, v3.y, v3.z, v3.w};
        s16x8 hv0, hv1, lv0, lv1;
#pragma unroll
        for (int q = 0; q < 8; ++q) {
          short h0 = bf16_rne(f[q]);
          hv0[q] = h0;
          lv0[q] = bf16_rne(f[q] - bf16_f(h0));
          short h1 = bf16_rne(f[q + 8]);
          hv1[q] = h1;
          lv1[q] = bf16_rne(f[q + 8] - bf16_f(h1));
        }
        const int ob = srow * 256 + sc0 * 2;
        const int sw = (srow & 7) << 4;
        *(s16x8*)(hinHi + (ob ^ sw))        = hv0;
        *(s16x8*)(hinHi + ((ob + 16) ^ sw)) = hv1;
        *(s16x8*)(hinLo + (ob ^ sw))        = lv0;
        *(s16x8*)(hinLo + ((ob + 16) ^ sw)) = lv1;
      }

      // gather-max: 4 rows per 32-lane group, 4 channels per lane
#pragma unroll
      for (int ni = 0; ni < 4; ++ni) {
        const int r = grp * 4 + ni;
        const int n = base + r;
        const int start = row_ptr[n], end = row_ptr[n + 1];
        float4 acc = make_float4(NI, NI, NI, NI);
        int j = start;
        for (; j + 4 <= end; j += 4) {
          int s0 = nbr[j], s1 = nbr[j + 1], s2 = nbr[j + 2], s3 = nbr[j + 3];
          float4 v0 = *(const float4*)(hin + (size_t)s0 * NFE + c4);
          float4 v1 = *(const float4*)(hin + (size_t)s1 * NFE + c4);
          float4 v2 = *(const float4*)(hin + (size_t)s2 * NFE + c4);
          float4 v3 = *(const float4*)(hin + (size_t)s3 * NFE + c4);
          acc = fmax4(acc, fmax4(fmax4(v0, v1), fmax4(v2, v3)));
        }
        for (; j < end; ++j) {
          acc = fmax4(acc, *(const float4*)(hin + (size_t)nbr[j] * NFE + c4));
        }
        if (start == end) acc = make_float4(0.f, 0.f, 0.f, 0.f);
        float f[4] = {acc.x, acc.y, acc.z, acc.w};
        s16x4 hv, lv;
#pragma unroll
        for (int q = 0; q < 4; ++q) {
          short h = bf16_rne(f[q]);
          hv[q] = h;
          lv[q] = bf16_rne(f[q] - bf16_f(h));
        }
        int off = r * 256 + c4 * 2;
        off ^= (r & 7) << 4;
        *(s16x4*)(aggHi + off) = hv;
        *(s16x4*)(aggLo + off) = lv;
      }
      __syncthreads();  // tile s published; consumers finished with buf[s&1]'s previous contents
    }
    __syncthreads();    // final: consumers process last tile
  } else {
    // ---------------- consumer ----------------
    const int w = wave - 4;      // col strip 32w
    const int l = t & 63;
    const int lr = l & 15;
    const int lk = (l >> 4) * 8;

    __syncthreads();             // wait for tile 0
    for (int s = 1; s <= nt; ++s) {
      const int base = (bid + (s - 1) * PIPE_GRID) * 32;
      const char* buf = smem + ((s - 1) & 1) * 32768;

      f32x4 acc[2][2] = {};      // [row tile][col tile]
#pragma unroll
      for (int seg = 0; seg < 2; ++seg) {
        const char* ahiB = buf + seg * 16384;
        const char* aloB = ahiB + 8192;
        const short* bhb = wbl + seg * 32768;
        const short* blb = bhb + 16384;
#pragma unroll
        for (int ks = 0; ks < 4; ++ks) {
          const int k0 = ks * 32;
          int offa0 = (lr) * 256 + (k0 + lk) * 2;      offa0 ^= ((lr) & 7) << 4;
          int offa1 = (16 + lr) * 256 + (k0 + lk) * 2; offa1 ^= ((16 + lr) & 7) << 4;
          s16x8 ah0 = *(const s16x8*)(ahiB + offa0);
          s16x8 ah1 = *(const s16x8*)(ahiB + offa1);
          s16x8 al0 = *(const s16x8*)(aloB + offa0);
          s16x8 al1 = *(const s16x8*)(aloB + offa1);
#pragma unroll
          for (int ct = 0; ct < 2; ++ct) {
            const int col = w * 32 + ct * 16 + lr;
            const s16x8 bh = *(const s16x8*)(bhb + col * 128 + k0 + lk);
            const s16x8 bl_ = *(const s16x8*)(blb + col * 128 + k0 + lk);
            acc[0][ct] = __builtin_amdgcn_mfma_f32_16x16x32_bf16(ah0, bh, acc[0][ct], 0, 0, 0);
            acc[1][ct] = __builtin_amdgcn_mfma_f32_16x16x32_bf16(ah1, bh, acc[1][ct], 0, 0, 0);
            acc[0][ct] = __builtin_amdgcn_mfma_f32_16x16x32_bf16(ah0, bl_, acc[0][ct], 0, 0, 0);
            acc[1][ct] = __builtin_amdgcn_mfma_f32_16x16x32_bf16(ah1, bl_, acc[1][ct], 0, 0, 0);
            acc[0][ct] = __builtin_amdgcn_mfma_f32_16x16x32_bf16(al0, bh, acc[0][ct], 0, 0, 0);
            acc[1][ct] = __builtin_amdgcn_mfma_f32_16x16x32_bf16(al1, bh, acc[1][ct], 0, 0, 0);
          }
        }
      }

      // epilogue: bias + leaky; C layout: col = lane&15, row = (lane>>4)*4 + reg
      const float bias0 = bl[w * 32 + lr];
      const float bias1 = bl[w * 32 + 16 + lr];
#pragma unroll
      for (int rt = 0; rt < 2; ++rt) {
#pragma unroll
        for (int r = 0; r < 4; ++r) {
          int node = base + 16 * rt + (l >> 4) * 4 + r;
          float* o = hout + (size_t)node * NFE + w * 32;
          o[lr]      = leaky(acc[rt][0][r] + bias0);
          o[16 + lr] = leaky(acc[rt][1][r] + bias1);
        }
      }
      __syncthreads();  // done reading buf[(s-1)&1]; producers may overwrite
    }
  }
}

// ---------------- fused output layer: gather-max + tiny GEMV + tanh ----------------

__global__ __launch_bounds__(256) void k_final_fused(const float* __restrict__ h,
                                                     const int* __restrict__ row_ptr,
                                                     const int* __restrict__ nbr,
                                                     const float* __restrict__ Wlo,
                                                     const float* __restrict__ blo,
                                                     const float* __restrict__ Wro,
                                                     float* __restrict__ out) {
  const int wave = threadIdx.x >> 6;
  const int lane = threadIdx.x & 63;
  const int n = blockIdx.x * 4 + wave;
  if (n >= NN) return;
  const int c2 = lane * 2;
  const int start = row_ptr[n], end = row_ptr[n + 1];
  const float NI = __int_as_float(0xFF800000);
  float ax = NI, ay = NI;
  int j = start;
  for (; j + 4 <= end; j += 4) {
    int s0 = nbr[j], s1 = nbr[j + 1], s2 = nbr[j + 2], s3 = nbr[j + 3];
    float2 v0 = *(const float2*)(h + (size_t)s0 * NFE + c2);
    float2 v1 = *(const float2*)(h + (size_t)s1 * NFE + c2);
    float2 v2 = *(const float2*)(h + (size_t)s2 * NFE + c2);
    float2 v3 = *(const float2*)(h + (size_t)s3 * NFE + c2);
    ax = fmaxf(ax, fmaxf(fmaxf(v0.x, v1.x), fmaxf(v2.x, v3.x)));
    ay = fmaxf(ay, fmaxf(fmaxf(v0.y, v1.y), fmaxf(v2.y, v3.y)));
  }
  for (; j < end; ++j) {
    float2 v = *(const float2*)(h + (size_t)nbr[j] * NFE + c2);
    ax = fmaxf(ax, v.x);
    ay = fmaxf(ay, v.y);
  }
  if (start == end) { ax = 0.f; ay = 0.f; }
  const float2 hv = *(const float2*)(h + (size_t)n * NFE + c2);
  float p[3];
#pragma unroll
  for (int o = 0; o < 3; ++o) {
    const float2 wl = *(const float2*)(Wlo + o * NFE + c2);
    const float2 wr = *(const float2*)(Wro + o * NFE + c2);
    p[o] = ax * wl.x + ay * wl.y + hv.x * wr.x + hv.y * wr.y;
#pragma unroll
    for (int off = 32; off; off >>= 1) p[o] += __shfl_down(p[o], off, 64);
  }
  if (lane == 0) {
#pragma unroll
    for (int o = 0; o < 3; ++o)
      out[(size_t)n * 3 + o] = tanhf(p[o] + blo[o]) * 0.5f;
  }
}

// ---------------- launch ----------------

extern "C" void kernel_launch(void* const* d_in, const int* in_sizes, int n_in,
                              void* d_out, int out_size, void* d_ws, size_t ws_size,
                              hipStream_t stream) {
  const float* x   = (const float*)d_in[0];
  const int*   ei  = (const int*)d_in[1];
  const float* Wl  = (const float*)d_in[2];
  const float* bl  = (const float*)d_in[3];
  const float* Wr  = (const float*)d_in[4];
  const float* Wlo = (const float*)d_in[5];
  const float* blo = (const float*)d_in[6];
  const float* Wro = (const float*)d_in[7];
  float* out = (float*)d_out;

  const int* src = ei;
  const int* dst = ei + NE;

  char* ws = (char*)d_ws;
  size_t off = 0;
  auto alloc = [&](size_t bytes) { void* p = ws + off; off = (off + bytes + 255) & ~(size_t)255; return p; };
  int* counts  = (int*)alloc(sizeof(int) * NN);
  int* cursor  = (int*)alloc(sizeof(int) * NN);
  int* row_ptr = (int*)alloc(sizeof(int) * (NN + 1));
  int* nbr     = (int*)alloc(sizeof(int) * NE);
  int* bsum    = (int*)alloc(sizeof(int) * 128);
  int* boff    = (int*)alloc(sizeof(int) * 128);
  short* wb    = (short*)alloc(sizeof(short) * 7 * 65536);
  const size_t hbytes = (size_t)NN * NFE * sizeof(float);
  float* hA  = (float*)alloc(hbytes);
  float* hB  = (float*)alloc(hbytes);

  const int EB = (NE + 255) / 256;

  k_prep_w<<<(7 * 32768 + 255) / 256, 256, 0, stream>>>(Wl, Wr, wb);
  k_zero_i32<<<(NN + 255) / 256, 256, 0, stream>>>(counts, NN);
  k_hist<<<EB, 256, 0, stream>>>(dst, counts);
  k_scan_sum<<<SCAN_NB, 256, 0, stream>>>(counts, bsum);
  k_scan_top<<<1, 128, 0, stream>>>(bsum, boff);
  k_scan_blk<<<SCAN_NB, 256, 0, stream>>>(counts, boff, row_ptr, cursor);
  k_fill<<<EB, 256, 0, stream>>>(src, dst, row_ptr, cursor, nbr);

  const float* hin = x;
  float* bufs[2] = {hA, hB};
  for (int i = 0; i < 7; ++i) {
    float* hout = bufs[i & 1];
    k_layer_pipe<<<PIPE_GRID, 512, 0, stream>>>(hin, row_ptr, nbr,
                                                wb + (size_t)i * 65536,
                                                bl + (size_t)i * NFE, hout);
    hin = hout;
  }

  k_final_fused<<<(NN + 3) / 4, 256, 0, stream>>>(hin, row_ptr, nbr, Wlo, blo, Wro, out);
}

// Round 9
// 1425.478 us; speedup vs baseline: 1.1117x; 1.0627x over previous
//
#include <hip/hip_runtime.h>
#include <hip/hip_bf16.h>
#include <math.h>

#define NN 100000
#define NE 1600000
#define NFE 128
#define SCAN_NB 98        // ceil(NN/1024)
#define FILL_CHUNK 8192
#define FILL_NCHUNK 196   // ceil(NE/FILL_CHUNK)
#define FILL_BUCKET 12500 // NN/8 exactly

using f32x4 = __attribute__((ext_vector_type(4))) float;
using s16x8 = __attribute__((ext_vector_type(8))) short;
using s16x4 = __attribute__((ext_vector_type(4))) short;

__device__ __forceinline__ short bf16_rne(float x) {
  unsigned u = __float_as_uint(x);
  unsigned r = u + 0x7FFFu + ((u >> 16) & 1u);
  return (short)(r >> 16);
}
__device__ __forceinline__ float bf16_f(short s) {
  return __uint_as_float(((unsigned)(unsigned short)s) << 16);
}
__device__ __forceinline__ float leaky(float v) {
  return v >= 0.0f ? v : 0.02f * v;
}
__device__ __forceinline__ float4 fmax4(float4 a, float4 b) {
  return make_float4(fmaxf(a.x, b.x), fmaxf(a.y, b.y), fmaxf(a.z, b.z), fmaxf(a.w, b.w));
}

// ---------------- CSR build (once per call) ----------------

__global__ __launch_bounds__(256) void k_zero_i32(int* __restrict__ p, int n) {
  int i = blockIdx.x * blockDim.x + threadIdx.x;
  if (i < n) p[i] = 0;
}

// XCD-binned histogram: block (x = bid&7, k = bid>>3) scans edge chunk k,
// counts only dst in bucket x -> counts slice stays L2-local on one XCD.
__global__ __launch_bounds__(256) void k_hist_binned(const int* __restrict__ dst,
                                                     int* __restrict__ counts) {
  const int x = blockIdx.x & 7;
  const int k = blockIdx.x >> 3;
  const int lo = x * FILL_BUCKET, hi = lo + FILL_BUCKET;
  const int eend = min(NE, (k + 1) * FILL_CHUNK);
  for (int e = k * FILL_CHUNK + threadIdx.x; e < eend; e += 256) {
    int d = dst[e];
    if (d >= lo && d < hi) atomicAdd(&counts[d], 1);
  }
}

__global__ __launch_bounds__(256) void k_scan_sum(const int* __restrict__ counts,
                                                  int* __restrict__ bsum) {
  const int t = threadIdx.x;
  const int base = blockIdx.x * 1024 + t * 4;
  int4 c = make_int4(0, 0, 0, 0);
  if (base + 3 < NN) c = *(const int4*)(counts + base);
  else {
    if (base + 0 < NN) c.x = counts[base + 0];
    if (base + 1 < NN) c.y = counts[base + 1];
    if (base + 2 < NN) c.z = counts[base + 2];
  }
  int s = c.x + c.y + c.z + c.w;
#pragma unroll
  for (int off = 32; off; off >>= 1) s += __shfl_down(s, off, 64);
  __shared__ int ws[4];
  if ((t & 63) == 0) ws[t >> 6] = s;
  __syncthreads();
  if (t == 0) bsum[blockIdx.x] = ws[0] + ws[1] + ws[2] + ws[3];
}

__global__ __launch_bounds__(128) void k_scan_top(const int* __restrict__ bsum,
                                                  int* __restrict__ boff) {
  __shared__ int v[128];
  const int t = threadIdx.x;
  int mine = (t < SCAN_NB) ? bsum[t] : 0;
  v[t] = mine;
  __syncthreads();
  for (int off = 1; off < 128; off <<= 1) {
    int u = (t >= off) ? v[t - off] : 0;
    __syncthreads();
    v[t] += u;
    __syncthreads();
  }
  if (t < SCAN_NB) boff[t] = v[t] - mine;  // exclusive
}

__global__ __launch_bounds__(256) void k_scan_blk(const int* __restrict__ counts,
                                                  const int* __restrict__ boff,
                                                  int* __restrict__ row_ptr,
                                                  int* __restrict__ cursor) {
  __shared__ int part[256];
  const int t = threadIdx.x;
  const int base = blockIdx.x * 1024 + t * 4;
  int4 c = make_int4(0, 0, 0, 0);
  if (base + 3 < NN) c = *(const int4*)(counts + base);
  else {
    if (base + 0 < NN) c.x = counts[base + 0];
    if (base + 1 < NN) c.y = counts[base + 1];
    if (base + 2 < NN) c.z = counts[base + 2];
  }
  const int s = c.x + c.y + c.z + c.w;
  part[t] = s;
  __syncthreads();
  for (int off = 1; off < 256; off <<= 1) {
    int u = (t >= off) ? part[t - off] : 0;
    __syncthreads();
    part[t] += u;
    __syncthreads();
  }
  int excl = boff[blockIdx.x] + part[t] - s;
  int4 r;
  r.x = excl;
  r.y = r.x + c.x;
  r.z = r.y + c.y;
  r.w = r.z + c.z;
  const int4 z = make_int4(0, 0, 0, 0);
  if (base + 3 < NN) {
    *(int4*)(row_ptr + base) = r;
    *(int4*)(cursor + base) = z;
  } else {
    if (base + 0 < NN) { row_ptr[base + 0] = r.x; cursor[base + 0] = 0; }
    if (base + 1 < NN) { row_ptr[base + 1] = r.y; cursor[base + 1] = 0; }
    if (base + 2 < NN) { row_ptr[base + 2] = r.z; cursor[base + 2] = 0; }
  }
  if (blockIdx.x == 0 && t == 0) row_ptr[NN] = NE;
}

// XCD-binned fill: bucket x's nbr slice (~800KB) and cursor slice (50KB)
// are written only by blocks with bid&7 == x (one XCD under %8 round-robin)
// -> write lines coalesce in that XCD's L2 instead of 16x amplification.
__global__ __launch_bounds__(256) void k_fill_binned(const int* __restrict__ src,
                                                     const int* __restrict__ dst,
                                                     const int* __restrict__ row_ptr,
                                                     int* __restrict__ cursor,
                                                     int* __restrict__ nbr) {
  const int x = blockIdx.x & 7;
  const int k = blockIdx.x >> 3;
  const int lo = x * FILL_BUCKET, hi = lo + FILL_BUCKET;
  const int eend = min(NE, (k + 1) * FILL_CHUNK);
  for (int e = k * FILL_CHUNK + threadIdx.x; e < eend; e += 256) {
    int d = dst[e];
    if (d >= lo && d < hi) {
      int p = atomicAdd(&cursor[d], 1);
      nbr[row_ptr[d] + p] = src[e];  // order within row nondeterministic; max is invariant
    }
  }
}

// ---------------- weight prep: f32 -> bf16 hi/lo ----------------

__global__ __launch_bounds__(256) void k_prep_w(const float* __restrict__ Wl,
                                                const float* __restrict__ Wr,
                                                short* __restrict__ wb) {
  int idx = blockIdx.x * 256 + threadIdx.x;
  if (idx >= 7 * 2 * 16384) return;
  int li = idx / 32768;
  int rem = idx % 32768;
  int seg = rem / 16384;
  int ok = rem % 16384;
  float v = seg ? Wr[li * 16384 + ok] : Wl[li * 16384 + ok];
  short hi = bf16_rne(v);
  short lo = bf16_rne(v - bf16_f(hi));
  short* base = wb + (size_t)li * 65536 + seg * 32768;
  base[ok] = hi;
  base[16384 + ok] = lo;
}

// ---------------- fused hidden layer (r5 structure — best measured) ----------------
// hout = leaky( (max_{s in N(n)} hin[s]) @ Wl^T + bl + hin @ Wr^T )

__global__ __launch_bounds__(256) void k_layer_fused(const float* __restrict__ hin,
                                                     const int* __restrict__ row_ptr,
                                                     const int* __restrict__ nbr,
                                                     const short* __restrict__ wbl,
                                                     const float* __restrict__ bl,
                                                     float* __restrict__ hout) {
  // LDS: 0=agg hi, 1=agg lo, 2=hin hi, 3=hin lo; each 32 rows x 128 k bf16 (8KB)
  // XOR swizzle on byte offsets: off ^= (row&7)<<4 (write and read)
  __shared__ __align__(16) char smem[4 * 8192];
  const int t = threadIdx.x;
  const int base = blockIdx.x * 32;

  // --- stage hin tile (root branch) ---
  {
    char* dhi = smem + 2 * 8192;
    char* dlo = smem + 3 * 8192;
#pragma unroll
    for (int i = 0; i < 2; ++i) {
      int c = t + 256 * i;
      int row = c >> 4;
      int kc = (c & 15) * 8;
      const float4* g = (const float4*)(hin + (size_t)(base + row) * NFE + kc);
      float4 v0 = g[0], v1 = g[1];
      float f[8] = {v0.x, v0.y, v0.z, v0.w, v1.x, v1.y, v1.z, v1.w};
      s16x8 hv, lv;
#pragma unroll
      for (int j = 0; j < 8; ++j) {
        short h = bf16_rne(f[j]);
        hv[j] = h;
        lv[j] = bf16_rne(f[j] - bf16_f(h));
      }
      int off = row * 256 + kc * 2;
      off ^= (row & 7) << 4;
      *(s16x8*)(dhi + off) = hv;
      *(s16x8*)(dlo + off) = lv;
    }
  }

  // --- gather-max directly into the A tile (neighbor branch) ---
  {
    char* ahi = smem;
    char* alo = smem + 8192;
    const int grp = t >> 5;        // 8 groups of 32 lanes
    const int lg = t & 31;
    const int c4 = lg << 2;        // 4 contiguous channels
    const float NI = __int_as_float(0xFF800000);
#pragma unroll
    for (int ni = 0; ni < 4; ++ni) {
      const int r = grp * 4 + ni;  // in-block row
      const int n = base + r;
      const int start = row_ptr[n], end = row_ptr[n + 1];
      float4 acc = make_float4(NI, NI, NI, NI);
      int j = start;
      for (; j + 4 <= end; j += 4) {
        int s0 = nbr[j], s1 = nbr[j + 1], s2 = nbr[j + 2], s3 = nbr[j + 3];
        float4 v0 = *(const float4*)(hin + (size_t)s0 * NFE + c4);
        float4 v1 = *(const float4*)(hin + (size_t)s1 * NFE + c4);
        float4 v2 = *(const float4*)(hin + (size_t)s2 * NFE + c4);
        float4 v3 = *(const float4*)(hin + (size_t)s3 * NFE + c4);
        acc = fmax4(acc, fmax4(fmax4(v0, v1), fmax4(v2, v3)));
      }
      for (; j < end; ++j) {
        int s = nbr[j];
        acc = fmax4(acc, *(const float4*)(hin + (size_t)s * NFE + c4));
      }
      if (start == end) acc = make_float4(0.f, 0.f, 0.f, 0.f);
      float f[4] = {acc.x, acc.y, acc.z, acc.w};
      s16x4 hv, lv;
#pragma unroll
      for (int q = 0; q < 4; ++q) {
        short h = bf16_rne(f[q]);
        hv[q] = h;
        lv[q] = bf16_rne(f[q] - bf16_f(h));
      }
      int off = r * 256 + c4 * 2;
      off ^= (r & 7) << 4;
      *(s16x4*)(ahi + off) = hv;
      *(s16x4*)(alo + off) = lv;
    }
  }
  __syncthreads();

  // --- split-bf16 MFMA: Ahi*Whi + Ahi*Wlo + Alo*Whi per branch ---
  const int w = t >> 6;
  const int l = t & 63;
  const int lr = l & 15;
  const int lk = (l >> 4) * 8;

  f32x4 acc[2][2] = {};

#pragma unroll
  for (int seg = 0; seg < 2; ++seg) {
    const char* ahi = smem + (seg * 2 + 0) * 8192;
    const char* alo = smem + (seg * 2 + 1) * 8192;
    const short* bhb = wbl + seg * 32768;
    const short* blb = wbl + seg * 32768 + 16384;
#pragma unroll
    for (int ks = 0; ks < 4; ++ks) {
      const int k0 = ks * 32;
      int offa0 = (lr) * 256 + (k0 + lk) * 2;      offa0 ^= ((lr) & 7) << 4;
      int offa1 = (16 + lr) * 256 + (k0 + lk) * 2; offa1 ^= ((16 + lr) & 7) << 4;
      s16x8 ah0 = *(const s16x8*)(ahi + offa0);
      s16x8 ah1 = *(const s16x8*)(ahi + offa1);
      s16x8 al0 = *(const s16x8*)(alo + offa0);
      s16x8 al1 = *(const s16x8*)(alo + offa1);
#pragma unroll
      for (int ct = 0; ct < 2; ++ct) {
        const int col = w * 32 + ct * 16 + lr;
        const s16x8 bh = *(const s16x8*)(bhb + col * 128 + k0 + lk);
        const s16x8 bl_ = *(const s16x8*)(blb + col * 128 + k0 + lk);
        acc[0][ct] = __builtin_amdgcn_mfma_f32_16x16x32_bf16(ah0, bh, acc[0][ct], 0, 0, 0);
        acc[1][ct] = __builtin_amdgcn_mfma_f32_16x16x32_bf16(ah1, bh, acc[1][ct], 0, 0, 0);
        acc[0][ct] = __builtin_amdgcn_mfma_f32_16x16x32_bf16(ah0, bl_, acc[0][ct], 0, 0, 0);
        acc[1][ct] = __builtin_amdgcn_mfma_f32_16x16x32_bf16(ah1, bl_, acc[1][ct], 0, 0, 0);
        acc[0][ct] = __builtin_amdgcn_mfma_f32_16x16x32_bf16(al0, bh, acc[0][ct], 0, 0, 0);
        acc[1][ct] = __builtin_amdgcn_mfma_f32_16x16x32_bf16(al1, bh, acc[1][ct], 0, 0, 0);
      }
    }
  }

  // epilogue: bias + leaky; C layout: col = lane&15, row = (lane>>4)*4 + reg
  const float bias0 = bl[w * 32 + lr];
  const float bias1 = bl[w * 32 + 16 + lr];
#pragma unroll
  for (int rt = 0; rt < 2; ++rt) {
#pragma unroll
    for (int r = 0; r < 4; ++r) {
      int node = base + 16 * rt + (l >> 4) * 4 + r;
      float* o = hout + (size_t)node * NFE + w * 32;
      o[lr]      = leaky(acc[rt][0][r] + bias0);
      o[16 + lr] = leaky(acc[rt][1][r] + bias1);
    }
  }
}

// ---------------- fused output layer: gather-max + tiny GEMV + tanh ----------------

__global__ __launch_bounds__(256) void k_final_fused(const float* __restrict__ h,
                                                     const int* __restrict__ row_ptr,
                                                     const int* __restrict__ nbr,
                                                     const float* __restrict__ Wlo,
                                                     const float* __restrict__ blo,
                                                     const float* __restrict__ Wro,
                                                     float* __restrict__ out) {
  const int wave = threadIdx.x >> 6;
  const int lane = threadIdx.x & 63;
  const int n = blockIdx.x * 4 + wave;
  if (n >= NN) return;
  const int c2 = lane * 2;
  const int start = row_ptr[n], end = row_ptr[n + 1];
  const float NI = __int_as_float(0xFF800000);
  float ax = NI, ay = NI;
  int j = start;
  for (; j + 4 <= end; j += 4) {
    int s0 = nbr[j], s1 = nbr[j + 1], s2 = nbr[j + 2], s3 = nbr[j + 3];
    float2 v0 = *(const float2*)(h + (size_t)s0 * NFE + c2);
    float2 v1 = *(const float2*)(h + (size_t)s1 * NFE + c2);
    float2 v2 = *(const float2*)(h + (size_t)s2 * NFE + c2);
    float2 v3 = *(const float2*)(h + (size_t)s3 * NFE + c2);
    ax = fmaxf(ax, fmaxf(fmaxf(v0.x, v1.x), fmaxf(v2.x, v3.x)));
    ay = fmaxf(ay, fmaxf(fmaxf(v0.y, v1.y), fmaxf(v2.y, v3.y)));
  }
  for (; j < end; ++j) {
    float2 v = *(const float2*)(h + (size_t)nbr[j] * NFE + c2);
    ax = fmaxf(ax, v.x);
    ay = fmaxf(ay, v.y);
  }
  if (start == end) { ax = 0.f; ay = 0.f; }
  const float2 hv = *(const float2*)(h + (size_t)n * NFE + c2);
  float p[3];
#pragma unroll
  for (int o = 0; o < 3; ++o) {
    const float2 wl = *(const float2*)(Wlo + o * NFE + c2);
    const float2 wr = *(const float2*)(Wro + o * NFE + c2);
    p[o] = ax * wl.x + ay * wl.y + hv.x * wr.x + hv.y * wr.y;
#pragma unroll
    for (int off = 32; off; off >>= 1) p[o] += __shfl_down(p[o], off, 64);
  }
  if (lane == 0) {
#pragma unroll
    for (int o = 0; o < 3; ++o)
      out[(size_t)n * 3 + o] = tanhf(p[o] + blo[o]) * 0.5f;
  }
}

// ---------------- launch ----------------

extern "C" void kernel_launch(void* const* d_in, const int* in_sizes, int n_in,
                              void* d_out, int out_size, void* d_ws, size_t ws_size,
                              hipStream_t stream) {
  const float* x   = (const float*)d_in[0];
  const int*   ei  = (const int*)d_in[1];
  const float* Wl  = (const float*)d_in[2];
  const float* bl  = (const float*)d_in[3];
  const float* Wr  = (const float*)d_in[4];
  const float* Wlo = (const float*)d_in[5];
  const float* blo = (const float*)d_in[6];
  const float* Wro = (const float*)d_in[7];
  float* out = (float*)d_out;

  const int* src = ei;
  const int* dst = ei + NE;

  char* ws = (char*)d_ws;
  size_t off = 0;
  auto alloc = [&](size_t bytes) { void* p = ws + off; off = (off + bytes + 255) & ~(size_t)255; return p; };
  int* counts  = (int*)alloc(sizeof(int) * NN);
  int* cursor  = (int*)alloc(sizeof(int) * NN);
  int* row_ptr = (int*)alloc(sizeof(int) * (NN + 1));
  int* nbr     = (int*)alloc(sizeof(int) * NE);
  int* bsum    = (int*)alloc(sizeof(int) * 128);
  int* boff    = (int*)alloc(sizeof(int) * 128);
  short* wb    = (short*)alloc(sizeof(short) * 7 * 65536);
  const size_t hbytes = (size_t)NN * NFE * sizeof(float);
  float* hA  = (float*)alloc(hbytes);
  float* hB  = (float*)alloc(hbytes);

  k_prep_w<<<(7 * 32768 + 255) / 256, 256, 0, stream>>>(Wl, Wr, wb);
  k_zero_i32<<<(NN + 255) / 256, 256, 0, stream>>>(counts, NN);
  k_hist_binned<<<8 * FILL_NCHUNK, 256, 0, stream>>>(dst, counts);
  k_scan_sum<<<SCAN_NB, 256, 0, stream>>>(counts, bsum);
  k_scan_top<<<1, 128, 0, stream>>>(bsum, boff);
  k_scan_blk<<<SCAN_NB, 256, 0, stream>>>(counts, boff, row_ptr, cursor);
  k_fill_binned<<<8 * FILL_NCHUNK, 256, 0, stream>>>(src, dst, row_ptr, cursor, nbr);

  const float* hin = x;
  float* bufs[2] = {hA, hB};
  for (int i = 0; i < 7; ++i) {
    float* hout = bufs[i & 1];
    k_layer_fused<<<NN / 32, 256, 0, stream>>>(hin, row_ptr, nbr,
                                               wb + (size_t)i * 65536,
                                               bl + (size_t)i * NFE, hout);
    hin = hout;
  }

  k_final_fused<<<(NN + 3) / 4, 256, 0, stream>>>(hin, row_ptr, nbr, Wlo, blo, Wro, out);
}